// Round 9
// baseline (146.980 us; speedup 1.0000x reference)
//
#include <hip/hip_runtime.h>
#include <hip/hip_bf16.h>

#define HIN 512
#define WIN 1024
#define NPIX (HIN * WIN)                // 524288 = 2^19
#define BATCH 4
#define CH 16
#define NPLANES (BATCH * CH)            // 64
#define NXCD 8
#define PLANES_PER_XCD (NPLANES / NXCD)
#define THREADS 256

typedef float vfloat4 __attribute__((ext_vector_type(4)));
typedef unsigned int vuint4 __attribute__((ext_vector_type(4)));

__device__ __forceinline__ float bf2f(unsigned short u) {
    unsigned int v = ((unsigned int)u) << 16;
    float f;
    __builtin_memcpy(&f, &v, 4);
    return f;
}

__device__ __forceinline__ unsigned short f2bf(float f) {
    __hip_bfloat16 h = __float2bfloat16(f);   // RNE
    unsigned short u;
    __builtin_memcpy(&u, &h, 2);
    return u;
}

// ---------------- Phase 1: [B][C][H][W] fp32 -> xt[B][H][W][C] bf16 ---------
// One block per (b, h) image row. Thread t owns 4 pixels (w = 4t..4t+3):
// 16 x vfloat4 nt loads (1 KB/wave/instruction), pack to bf16, store 128 B
// contiguous per thread (8 x vuint4).
__global__ __launch_bounds__(256) void transpose_cl_bf16(
    const float* __restrict__ x, __hip_bfloat16* __restrict__ xt)
{
    const int t = threadIdx.x;
    const int bk = blockIdx.x;           // 0 .. B*HIN-1
    const int h = bk & (HIN - 1);
    const int b = bk >> 9;
    const int w0 = t * 4;

    const size_t cstride = (size_t)HIN * WIN;
    const float* src = x + (((size_t)b * CH) * HIN + h) * WIN + w0;

    vfloat4 rv[CH];
#pragma unroll
    for (int c = 0; c < CH; ++c)
        rv[c] = __builtin_nontemporal_load(
            reinterpret_cast<const vfloat4*>(src + (size_t)c * cstride));

    // us[k][c]: pixel k's channel c (bf16)
    unsigned short us[4][CH];
#pragma unroll
    for (int c = 0; c < CH; ++c) {
        us[0][c] = f2bf(rv[c].x);
        us[1][c] = f2bf(rv[c].y);
        us[2][c] = f2bf(rv[c].z);
        us[3][c] = f2bf(rv[c].w);
    }

    __hip_bfloat16* dst = xt + (((size_t)b * HIN + h) * WIN + w0) * CH;
    vuint4* d4 = reinterpret_cast<vuint4*>(dst);  // 128 B per thread, contiguous
#pragma unroll
    for (int k = 0; k < 4; ++k) {
        vuint4 lo, hi;
        __builtin_memcpy(&lo, &us[k][0], 16);
        __builtin_memcpy(&hi, &us[k][8], 16);
        d4[2 * k] = lo;
        d4[2 * k + 1] = hi;
    }
}

// ---------------- Phase 2: 2-lane team per (b, pixel), 2 pixels/thread ------
// blockIdx&7 -> XCD; XCD pair (2b, 2b+1) owns batch b (per-XCD random set =
// 16 MB). Lane ci in {0,1} handles 8 channels: one 16B load per corner.
// map loads are non-temporal (pure stream; don't evict xt from L2).
__global__ __launch_bounds__(256) void gather_cl_bf16(
    const __hip_bfloat16* __restrict__ xt,  // [B][H][W][C] bf16
    const float* __restrict__ sample_map,   // [NPIX][2]
    float* __restrict__ out)                // [B][C][NPIX]
{
    const int t = threadIdx.x;
    const int xcd = blockIdx.x & (NXCD - 1);
    const int j = blockIdx.x >> 3;        // 0 .. 1023
    const int b = xcd >> 1;
    const int half = xcd & 1;
    const int ci = t & 1;
    const int pi = t >> 1;
    const int pbase = half * (NPIX / 2) + j * 256 + pi;

    const double* __restrict__ smap = reinterpret_cast<const double*>(sample_map);
    const size_t ibase = (size_t)b * ((size_t)NPIX * CH) + (size_t)ci * 8;

    double sd0 = __builtin_nontemporal_load(&smap[pbase]);
    double sd1 = __builtin_nontemporal_load(&smap[pbase + 128]);

    float s0[2], s1[2];
    __builtin_memcpy(s0, &sd0, 8);
    __builtin_memcpy(s1, &sd1, 8);

    float x0f0 = floorf(s0[0]), y0f0 = floorf(s0[1]);
    float dx0 = s0[0] - x0f0, dy0 = s0[1] - y0f0;
    int x00 = min(max((int)x0f0, 0), WIN - 1);
    int y00 = min(max((int)y0f0, 0), HIN - 1);
    int x10 = min(max((int)x0f0 + 1, 0), WIN - 1);
    int y10 = min(max((int)y0f0 + 1, 0), HIN - 1);

    float x0f1 = floorf(s1[0]), y0f1 = floorf(s1[1]);
    float dx1 = s1[0] - x0f1, dy1 = s1[1] - y0f1;
    int x01 = min(max((int)x0f1, 0), WIN - 1);
    int y01 = min(max((int)y0f1, 0), HIN - 1);
    int x11 = min(max((int)x0f1 + 1, 0), WIN - 1);
    int y11 = min(max((int)y0f1 + 1, 0), HIN - 1);

    const vuint4 a00 = *reinterpret_cast<const vuint4*>(&xt[ibase + (size_t)(y00 * WIN + x00) * CH]);
    const vuint4 a10 = *reinterpret_cast<const vuint4*>(&xt[ibase + (size_t)(y00 * WIN + x10) * CH]);
    const vuint4 a01 = *reinterpret_cast<const vuint4*>(&xt[ibase + (size_t)(y10 * WIN + x00) * CH]);
    const vuint4 a11 = *reinterpret_cast<const vuint4*>(&xt[ibase + (size_t)(y10 * WIN + x10) * CH]);
    const vuint4 b00 = *reinterpret_cast<const vuint4*>(&xt[ibase + (size_t)(y01 * WIN + x01) * CH]);
    const vuint4 b10 = *reinterpret_cast<const vuint4*>(&xt[ibase + (size_t)(y01 * WIN + x11) * CH]);
    const vuint4 b01 = *reinterpret_cast<const vuint4*>(&xt[ibase + (size_t)(y11 * WIN + x01) * CH]);
    const vuint4 b11 = *reinterpret_cast<const vuint4*>(&xt[ibase + (size_t)(y11 * WIN + x11) * CH]);

    const float w00a = (1.0f - dx0) * (1.0f - dy0);
    const float w10a = dx0 * (1.0f - dy0);
    const float w01a = (1.0f - dx0) * dy0;
    const float w11a = dx0 * dy0;
    const float w00b = (1.0f - dx1) * (1.0f - dy1);
    const float w10b = dx1 * (1.0f - dy1);
    const float w01b = (1.0f - dx1) * dy1;
    const float w11b = dx1 * dy1;

    unsigned short h00[8], h10[8], h01[8], h11[8];
    float* o = out + ((size_t)(b * CH + ci * 8)) * NPIX + pbase;

    __builtin_memcpy(h00, &a00, 16);
    __builtin_memcpy(h10, &a10, 16);
    __builtin_memcpy(h01, &a01, 16);
    __builtin_memcpy(h11, &a11, 16);
#pragma unroll
    for (int k = 0; k < 8; ++k) {
        float v = bf2f(h00[k]) * w00a + bf2f(h10[k]) * w10a
                + bf2f(h01[k]) * w01a + bf2f(h11[k]) * w11a;
        __builtin_nontemporal_store(v, o + (size_t)k * NPIX);
    }

    __builtin_memcpy(h00, &b00, 16);
    __builtin_memcpy(h10, &b10, 16);
    __builtin_memcpy(h01, &b01, 16);
    __builtin_memcpy(h11, &b11, 16);
#pragma unroll
    for (int k = 0; k < 8; ++k) {
        float v = bf2f(h00[k]) * w00b + bf2f(h10[k]) * w10b
                + bf2f(h01[k]) * w01b + bf2f(h11[k]) * w11b;
        __builtin_nontemporal_store(v, o + (size_t)k * NPIX + 128);
    }
}

// ---------------- Fallback (round-4 8-pass kernel) if ws too small ----------
#define BLOCKS_PER_XCD 256
#define NBLOCKS (NXCD * BLOCKS_PER_XCD)
#define CHUNK (NPIX / BLOCKS_PER_XCD)
#define PXT (CHUNK / THREADS)

__global__ __launch_bounds__(256) void unresample_pass(
    const float* __restrict__ x, const float* __restrict__ sample_map,
    float* __restrict__ out, int pass)
{
    const int t = threadIdx.x;
    const int i = blockIdx.x;
    const int xcd = i & (NXCD - 1);
    const int j = i >> 3;
    const int base = j * CHUNK;
    const int bc = xcd * PLANES_PER_XCD + pass;

    const float* __restrict__ pl = x + (size_t)bc * NPIX;
    float* __restrict__ op = out + (size_t)bc * NPIX + base;
    const double* __restrict__ smap = reinterpret_cast<const double*>(sample_map);

#pragma unroll
    for (int kk = 0; kk < PXT; ++kk) {
        const int off = kk * THREADS + t;
        const int p = base + off;
        double sd = __builtin_nontemporal_load(&smap[p]);
        float s[2];
        __builtin_memcpy(s, &sd, 8);
        float sx = s[0], sy = s[1];
        float x0f = floorf(sx), y0f = floorf(sy);
        float dx = sx - x0f, dy = sy - y0f;
        int x0 = (int)x0f, y0 = (int)y0f;
        int x0c = min(max(x0, 0), WIN - 1);
        int y0c = min(max(y0, 0), HIN - 1);
        int x1c = min(max(x0 + 1, 0), WIN - 1);
        int y1c = min(max(y0 + 1, 0), HIN - 1);
        float w00 = (1.0f - dx) * (1.0f - dy);
        float w10 = dx * (1.0f - dy);
        float w01 = (1.0f - dx) * dy;
        float w11 = dx * dy;
        const int r0 = y0c * WIN, r1 = y1c * WIN;
        float v = pl[r0 + x0c] * w00 + pl[r0 + x1c] * w10
                + pl[r1 + x0c] * w01 + pl[r1 + x1c] * w11;
        __builtin_nontemporal_store(v, &op[off]);
    }
}

extern "C" void kernel_launch(void* const* d_in, const int* in_sizes, int n_in,
                              void* d_out, int out_size, void* d_ws, size_t ws_size,
                              hipStream_t stream) {
    const float* x = (const float*)d_in[0];
    const float* sample_map = (const float*)d_in[1];
    float* out = (float*)d_out;

    const size_t need = (size_t)BATCH * NPIX * CH * sizeof(__hip_bfloat16); // 64 MB
    if (ws_size >= need) {
        __hip_bfloat16* xt = (__hip_bfloat16*)d_ws;
        transpose_cl_bf16<<<BATCH * HIN, THREADS, 0, stream>>>(x, xt);
        const int nthreads = BATCH * NPIX;                        // 2 lanes/px, 2 px/thread
        gather_cl_bf16<<<nthreads / THREADS, THREADS, 0, stream>>>(xt, sample_map, out);
    } else {
        for (int pass = 0; pass < PLANES_PER_XCD; ++pass)
            unresample_pass<<<NBLOCKS, THREADS, 0, stream>>>(x, sample_map, out, pass);
    }
}

// Round 11
// 135.467 us; speedup vs baseline: 1.0850x; 1.0850x over previous
//
#include <hip/hip_runtime.h>
#include <hip/hip_bf16.h>

#define HIN 512
#define WIN 1024
#define NPIX (HIN * WIN)                // 524288 = 2^19
#define BATCH 4
#define CH 16
#define NPLANES (BATCH * CH)            // 64
#define NXCD 8
#define PLANES_PER_XCD (NPLANES / NXCD)
#define THREADS 256

typedef float vfloat4 __attribute__((ext_vector_type(4)));
typedef unsigned int vuint4 __attribute__((ext_vector_type(4)));

__device__ __forceinline__ float bf2f(unsigned short u) {
    unsigned int v = ((unsigned int)u) << 16;
    float f;
    __builtin_memcpy(&f, &v, 4);
    return f;
}

__device__ __forceinline__ unsigned short f2bf(float f) {
    __hip_bfloat16 h = __float2bfloat16(f);   // RNE
    unsigned short u;
    __builtin_memcpy(&u, &h, 2);
    return u;
}

// ---------------- Phase 1: [B][C][H][W] fp32 -> xt[B][H][W][C] bf16 ---------
// One block per (b, h) row. Thread t loads pixels 4t..4t+3 for all 16 channels
// (16 x vfloat4, 1 KB/wave/instruction), packs to bf16 (8 vuint4 chunks,
// global chunk index g = 8t + j), stages through LDS with an XOR slot swizzle,
// then stores the 32 KB row tile with lane-contiguous 1 KB-per-wave stores.
__global__ __launch_bounds__(256) void transpose_cl_bf16(
    const float* __restrict__ x, __hip_bfloat16* __restrict__ xt)
{
    __shared__ vuint4 lds[THREADS * 8];   // 32 KB
    const int t = threadIdx.x;
    const int bk = blockIdx.x;            // 0 .. B*HIN-1
    const int h = bk & (HIN - 1);
    const int b = bk >> 9;
    const int w0 = t * 4;

    const size_t cstride = (size_t)HIN * WIN;
    const float* src = x + (((size_t)b * CH) * HIN + h) * WIN + w0;

    vfloat4 rv[CH];
#pragma unroll
    for (int c = 0; c < CH; ++c)
        rv[c] = __builtin_nontemporal_load(
            reinterpret_cast<const vfloat4*>(src + (size_t)c * cstride));

    // us[k][c]: pixel k's channel c (bf16)
    unsigned short us[4][CH];
#pragma unroll
    for (int c = 0; c < CH; ++c) {
        us[0][c] = f2bf(rv[c].x);
        us[1][c] = f2bf(rv[c].y);
        us[2][c] = f2bf(rv[c].z);
        us[3][c] = f2bf(rv[c].w);
    }

    // chunk j = (pixel<<1)|half; global row chunk g = 8t + j.
    // slot swizzle (j+t)&7 spreads the 8 bank-groups on both sides.
#pragma unroll
    for (int j = 0; j < 8; ++j) {
        vuint4 v;
        __builtin_memcpy(&v, &us[j >> 1][(j & 1) * 8], 16);
        lds[t * 8 + ((j + t) & 7)] = v;
    }
    __syncthreads();

    // store step s: thread t writes row chunk g = s*256 + t (wave: 1 KB dense)
    // source: tt = g>>3 = s*32 + (t>>3), j = g&7 = t&7, slot (j+tt)&7
    vuint4* drow = reinterpret_cast<vuint4*>(xt + (((size_t)b * HIN + h) * WIN) * CH);
#pragma unroll
    for (int s = 0; s < 8; ++s) {
        const int tt = s * 32 + (t >> 3);
        const int j = t & 7;
        vuint4 v = lds[tt * 8 + ((j + tt) & 7)];
        drow[s * 256 + t] = v;
    }
}

// ---------------- Phase 2: 2-lane team per (b, pixel), 2 pixels/thread ------
// blockIdx&7 -> XCD; XCD pair (2b, 2b+1) owns batch b. Lane ci in {0,1}
// handles 8 channels: one 16B load per corner. nt map loads (pure stream).
__global__ __launch_bounds__(256) void gather_cl_bf16(
    const __hip_bfloat16* __restrict__ xt,  // [B][H][W][C] bf16
    const float* __restrict__ sample_map,   // [NPIX][2]
    float* __restrict__ out)                // [B][C][NPIX]
{
    const int t = threadIdx.x;
    const int xcd = blockIdx.x & (NXCD - 1);
    const int j = blockIdx.x >> 3;        // 0 .. 1023
    const int b = xcd >> 1;
    const int half = xcd & 1;
    const int ci = t & 1;
    const int pi = t >> 1;
    const int pbase = half * (NPIX / 2) + j * 256 + pi;

    const double* __restrict__ smap = reinterpret_cast<const double*>(sample_map);
    const size_t ibase = (size_t)b * ((size_t)NPIX * CH) + (size_t)ci * 8;

    double sd0 = __builtin_nontemporal_load(&smap[pbase]);
    double sd1 = __builtin_nontemporal_load(&smap[pbase + 128]);

    float s0[2], s1[2];
    __builtin_memcpy(s0, &sd0, 8);
    __builtin_memcpy(s1, &sd1, 8);

    float x0f0 = floorf(s0[0]), y0f0 = floorf(s0[1]);
    float dx0 = s0[0] - x0f0, dy0 = s0[1] - y0f0;
    int x00 = min(max((int)x0f0, 0), WIN - 1);
    int y00 = min(max((int)y0f0, 0), HIN - 1);
    int x10 = min(max((int)x0f0 + 1, 0), WIN - 1);
    int y10 = min(max((int)y0f0 + 1, 0), HIN - 1);

    float x0f1 = floorf(s1[0]), y0f1 = floorf(s1[1]);
    float dx1 = s1[0] - x0f1, dy1 = s1[1] - y0f1;
    int x01 = min(max((int)x0f1, 0), WIN - 1);
    int y01 = min(max((int)y0f1, 0), HIN - 1);
    int x11 = min(max((int)x0f1 + 1, 0), WIN - 1);
    int y11 = min(max((int)y0f1 + 1, 0), HIN - 1);

    const vuint4 a00 = *reinterpret_cast<const vuint4*>(&xt[ibase + (size_t)(y00 * WIN + x00) * CH]);
    const vuint4 a10 = *reinterpret_cast<const vuint4*>(&xt[ibase + (size_t)(y00 * WIN + x10) * CH]);
    const vuint4 a01 = *reinterpret_cast<const vuint4*>(&xt[ibase + (size_t)(y10 * WIN + x00) * CH]);
    const vuint4 a11 = *reinterpret_cast<const vuint4*>(&xt[ibase + (size_t)(y10 * WIN + x10) * CH]);
    const vuint4 b00 = *reinterpret_cast<const vuint4*>(&xt[ibase + (size_t)(y01 * WIN + x01) * CH]);
    const vuint4 b10 = *reinterpret_cast<const vuint4*>(&xt[ibase + (size_t)(y01 * WIN + x11) * CH]);
    const vuint4 b01 = *reinterpret_cast<const vuint4*>(&xt[ibase + (size_t)(y11 * WIN + x01) * CH]);
    const vuint4 b11 = *reinterpret_cast<const vuint4*>(&xt[ibase + (size_t)(y11 * WIN + x11) * CH]);

    const float w00a = (1.0f - dx0) * (1.0f - dy0);
    const float w10a = dx0 * (1.0f - dy0);
    const float w01a = (1.0f - dx0) * dy0;
    const float w11a = dx0 * dy0;
    const float w00b = (1.0f - dx1) * (1.0f - dy1);
    const float w10b = dx1 * (1.0f - dy1);
    const float w01b = (1.0f - dx1) * dy1;
    const float w11b = dx1 * dy1;

    unsigned short h00[8], h10[8], h01[8], h11[8];
    float* o = out + ((size_t)(b * CH + ci * 8)) * NPIX + pbase;

    __builtin_memcpy(h00, &a00, 16);
    __builtin_memcpy(h10, &a10, 16);
    __builtin_memcpy(h01, &a01, 16);
    __builtin_memcpy(h11, &a11, 16);
#pragma unroll
    for (int k = 0; k < 8; ++k) {
        float v = bf2f(h00[k]) * w00a + bf2f(h10[k]) * w10a
                + bf2f(h01[k]) * w01a + bf2f(h11[k]) * w11a;
        __builtin_nontemporal_store(v, o + (size_t)k * NPIX);
    }

    __builtin_memcpy(h00, &b00, 16);
    __builtin_memcpy(h10, &b10, 16);
    __builtin_memcpy(h01, &b01, 16);
    __builtin_memcpy(h11, &b11, 16);
#pragma unroll
    for (int k = 0; k < 8; ++k) {
        float v = bf2f(h00[k]) * w00b + bf2f(h10[k]) * w10b
                + bf2f(h01[k]) * w01b + bf2f(h11[k]) * w11b;
        __builtin_nontemporal_store(v, o + (size_t)k * NPIX + 128);
    }
}

// ---------------- Fallback (round-4 8-pass kernel) if ws too small ----------
#define BLOCKS_PER_XCD 256
#define NBLOCKS (NXCD * BLOCKS_PER_XCD)
#define CHUNK (NPIX / BLOCKS_PER_XCD)
#define PXT (CHUNK / THREADS)

__global__ __launch_bounds__(256) void unresample_pass(
    const float* __restrict__ x, const float* __restrict__ sample_map,
    float* __restrict__ out, int pass)
{
    const int t = threadIdx.x;
    const int i = blockIdx.x;
    const int xcd = i & (NXCD - 1);
    const int j = i >> 3;
    const int base = j * CHUNK;
    const int bc = xcd * PLANES_PER_XCD + pass;

    const float* __restrict__ pl = x + (size_t)bc * NPIX;
    float* __restrict__ op = out + (size_t)bc * NPIX + base;
    const double* __restrict__ smap = reinterpret_cast<const double*>(sample_map);

#pragma unroll
    for (int kk = 0; kk < PXT; ++kk) {
        const int off = kk * THREADS + t;
        const int p = base + off;
        double sd = __builtin_nontemporal_load(&smap[p]);
        float s[2];
        __builtin_memcpy(s, &sd, 8);
        float sx = s[0], sy = s[1];
        float x0f = floorf(sx), y0f = floorf(sy);
        float dx = sx - x0f, dy = sy - y0f;
        int x0 = (int)x0f, y0 = (int)y0f;
        int x0c = min(max(x0, 0), WIN - 1);
        int y0c = min(max(y0, 0), HIN - 1);
        int x1c = min(max(x0 + 1, 0), WIN - 1);
        int y1c = min(max(y0 + 1, 0), HIN - 1);
        float w00 = (1.0f - dx) * (1.0f - dy);
        float w10 = dx * (1.0f - dy);
        float w01 = (1.0f - dx) * dy;
        float w11 = dx * dy;
        const int r0 = y0c * WIN, r1 = y1c * WIN;
        float v = pl[r0 + x0c] * w00 + pl[r0 + x1c] * w10
                + pl[r1 + x0c] * w01 + pl[r1 + x1c] * w11;
        __builtin_nontemporal_store(v, &op[off]);
    }
}

extern "C" void kernel_launch(void* const* d_in, const int* in_sizes, int n_in,
                              void* d_out, int out_size, void* d_ws, size_t ws_size,
                              hipStream_t stream) {
    const float* x = (const float*)d_in[0];
    const float* sample_map = (const float*)d_in[1];
    float* out = (float*)d_out;

    const size_t need = (size_t)BATCH * NPIX * CH * sizeof(__hip_bfloat16); // 64 MB
    if (ws_size >= need) {
        __hip_bfloat16* xt = (__hip_bfloat16*)d_ws;
        transpose_cl_bf16<<<BATCH * HIN, THREADS, 0, stream>>>(x, xt);
        const int nthreads = BATCH * NPIX;                        // 2 lanes/px, 2 px/thread
        gather_cl_bf16<<<nthreads / THREADS, THREADS, 0, stream>>>(xt, sample_map, out);
    } else {
        for (int pass = 0; pass < PLANES_PER_XCD; ++pass)
            unresample_pass<<<NBLOCKS, THREADS, 0, stream>>>(x, sample_map, out, pass);
    }
}